// Round 1
// baseline (338.511 us; speedup 1.0000x reference)
//
#include <hip/hip_runtime.h>
#include <hip/hip_bf16.h>
#include <math.h>

#define DEV __device__ __forceinline__

typedef __attribute__((ext_vector_type(8))) short short8;
typedef __attribute__((ext_vector_type(4))) float f32x4;

DEV unsigned short f2bf(float f) {
  unsigned u = __float_as_uint(f);
  u = u + 0x7fffu + ((u >> 16) & 1u);
  return (unsigned short)(u >> 16);
}

DEV float softplus_f(float x) {
  return (x > 20.f) ? x : log1pf(expf(x));
}

// async global->LDS, 16B per lane. LDS dest must be wave-uniform base (+lane*16 by HW).
#define GL16(gp, lp) __builtin_amdgcn_global_load_lds( \
    (const __attribute__((address_space(1))) unsigned int*)(gp), \
    (__attribute__((address_space(3))) unsigned int*)(lp), 16, 0, 0)

// ---------------------------------------------------------------- conversions
__global__ __launch_bounds__(256) void k_conv(const float* __restrict__ in,
                                              unsigned short* __restrict__ out, int n4) {
  int i = blockIdx.x * 256 + threadIdx.x;
  if (i >= n4) return;
  const float4 v = reinterpret_cast<const float4*>(in)[i];
  ushort4 o;
  o.x = f2bf(v.x); o.y = f2bf(v.y); o.z = f2bf(v.z); o.w = f2bf(v.w);
  reinterpret_cast<ushort4*>(out)[i] = o;
}

// ---------------------------------------------------------------- small prep
// bwss[h,s] = sqrt(softmax(band_logits[h,:])[s] + 1e-8) * sqrt(softplus(phase_bias[h]) / 8)
// gpos[h,s] = softplus(gamma[h,s])
__global__ void k_prep_small(const float* __restrict__ band_logits,
                             const float* __restrict__ phase_bias,
                             const float* __restrict__ gamma,
                             float* __restrict__ bwss, float* __restrict__ gpos) {
  const int lane = threadIdx.x;  // 64 threads, 1 wave
  for (int h = 0; h < 16; ++h) {
    float bl = band_logits[h * 64 + lane];
    float mx = bl;
#pragma unroll
    for (int m = 1; m < 64; m <<= 1) mx = fmaxf(mx, __shfl_xor(mx, m));
    float e = expf(bl - mx);
    float sm = e;
#pragma unroll
    for (int m = 1; m < 64; m <<= 1) sm += __shfl_xor(sm, m);
    float ps = softplus_f(phase_bias[h]);
    float alpha = sqrtf(ps * 0.125f);
    bwss[h * 64 + lane] = sqrtf(e / sm + 1e-8f) * alpha;
    gpos[h * 64 + lane] = softplus_f(gamma[h * 64 + lane]);
  }
}

// ---------------------------------------------------------------- scale + features
// per (b, l-tile of 64): magn = mag_pl/(mean_s+1e-8); scale[b,h,l]=1+0.5*tanh(magn·gpos[h]);
// feat[b,h,l,0:64]=bwss[h,s]*cos_pl ; feat[b,h,l,64:128]=bwss[h,s]*sin_pl  (bf16)
__global__ __launch_bounds__(256) void k_prep(
    const float* __restrict__ cos_phi, const float* __restrict__ sin_phi,
    const float* __restrict__ mag, const float* __restrict__ gpos,
    const float* __restrict__ bwss, float* __restrict__ scaleB,
    unsigned short* __restrict__ feat) {
  const int b = blockIdx.x >> 4;
  const int l0 = (blockIdx.x & 15) << 6;
  const int t = threadIdx.x;
  __shared__ float cosL[64][65];
  __shared__ float sinL[64][65];
  __shared__ float magL[64][65];
  __shared__ float psum[4][64];
  __shared__ float minv[64];
  const size_t boff = (size_t)b * 65536;  // [B,S,L] stride
  for (int it = 0; it < 16; ++it) {
    const int s = it * 4 + (t >> 6), l = t & 63;
    const size_t g = boff + (size_t)s * 1024 + l0 + l;
    cosL[s][l] = cos_phi[g];
    sinL[s][l] = sin_phi[g];
    magL[s][l] = mag[g];
  }
  __syncthreads();
  {
    const int l = t & 63, g = t >> 6;
    float acc = 0.f;
    for (int i = 0; i < 16; ++i) acc += magL[g * 16 + i][l];
    psum[g][l] = acc;
  }
  __syncthreads();
  if (t < 64) {
    float mean = (psum[0][t] + psum[1][t] + psum[2][t] + psum[3][t]) * (1.f / 64.f);
    minv[t] = 1.f / (mean + 1e-8f);
  }
  __syncthreads();
  {
    const int l = t & 63;
    const float iv = minv[l];
    for (int hh = 0; hh < 4; ++hh) {
      const int hidx = ((t >> 6) << 2) + hh;
      float acc = 0.f;
      for (int s = 0; s < 64; ++s) acc += magL[s][l] * gpos[hidx * 64 + s];
      const float tnh = tanhf(acc * iv);
      scaleB[(size_t)(((b << 4) + hidx) << 10) + l0 + l] = 1.f + 0.5f * tnh;
    }
  }
  const int l = t >> 2, sq = (t & 3) << 4;
  for (int hh = 0; hh < 16; ++hh) {
    unsigned short* fp = feat + ((size_t)(((b << 4) + hh) << 10) + l0 + l) * 128;
#pragma unroll
    for (int j = 0; j < 16; ++j) {
      const int s = sq + j;
      const float bw = bwss[hh * 64 + s];
      fp[s] = f2bf(bw * cosL[s][l]);
      fp[64 + s] = f2bf(bw * sinL[s][l]);
    }
  }
}

// ---------------------------------------------------------------- bf16 MFMA GEMM (B^T), 128x128 tile, BK=32
// MODE 0: QKV fused (N=3072). epilogue: (+bias)*scale; q also *0.125; v stored transposed.
// MODE 1: O-proj (N=1024). epilogue: +bo +residual -> xout (f32).
template <int MODE>
__global__ __launch_bounds__(256) void k_gemm(
    const unsigned short* __restrict__ A, const unsigned short* __restrict__ Bt,
    int Ntiles, int K,
    const float* __restrict__ bq, const float* __restrict__ bk,
    const float* __restrict__ bv, const float* __restrict__ scaleB,
    unsigned short* __restrict__ qbuf, unsigned short* __restrict__ kbuf,
    unsigned short* __restrict__ vT,
    const float* __restrict__ bo, const float* __restrict__ resid,
    float* __restrict__ xout) {
  __shared__ __align__(16) short As[128 * 32];
  __shared__ __align__(16) short Bs[128 * 32];
  const int t = threadIdx.x;
  const int lane = t & 63;
  const int w = t >> 6;
  const int tm = (blockIdx.x / Ntiles) << 7;
  const int tn = (blockIdx.x % Ntiles) << 7;
  const int wR = (w >> 1) << 6;
  const int wC = (w & 1) << 6;
  const int rowS = t >> 2;        // staging row within 64-row pass
  const int offS = (t & 3) << 3;  // staging k-offset (elements)
  const int ka = (lane >> 4) << 3;
  const int lm = lane & 15;

  const f32x4 vzero = {0.f, 0.f, 0.f, 0.f};
  f32x4 acc[4][4];
#pragma unroll
  for (int i = 0; i < 4; ++i)
#pragma unroll
    for (int j = 0; j < 4; ++j) acc[i][j] = vzero;

  for (int kt = 0; kt < K; kt += 32) {
    __syncthreads();
#pragma unroll
    for (int p = 0; p < 2; ++p) {
      GL16(A + (size_t)(tm + p * 64 + rowS) * K + kt + offS, (char*)As + p * 4096 + w * 1024);
      GL16(Bt + (size_t)(tn + p * 64 + rowS) * K + kt + offS, (char*)Bs + p * 4096 + w * 1024);
    }
    __syncthreads();
    short8 af[4], bf[4];
#pragma unroll
    for (int mt = 0; mt < 4; ++mt) af[mt] = *(const short8*)&As[(wR + mt * 16 + lm) * 32 + ka];
#pragma unroll
    for (int nt = 0; nt < 4; ++nt) bf[nt] = *(const short8*)&Bs[(wC + nt * 16 + lm) * 32 + ka];
#pragma unroll
    for (int mt = 0; mt < 4; ++mt)
#pragma unroll
      for (int nt = 0; nt < 4; ++nt)
        acc[mt][nt] = __builtin_amdgcn_mfma_f32_16x16x32_bf16(af[mt], bf[nt], acc[mt][nt], 0, 0, 0);
  }

#pragma unroll
  for (int mt = 0; mt < 4; ++mt) {
#pragma unroll
    for (int r = 0; r < 4; ++r) {
      const int row = tm + wR + mt * 16 + ((lane >> 4) << 2) + r;
#pragma unroll
      for (int nt = 0; nt < 4; ++nt) {
        const int col = tn + wC + nt * 16 + lm;
        float v = acc[mt][nt][r];
        if (MODE == 0) {
          const int b = row >> 10, l = row & 1023;
          const int sect = col >> 10, jj = col & 1023;
          const int h = jj >> 6, hd = jj & 63;
          const int bh = (b << 4) + h;
          const float sc = scaleB[((size_t)bh << 10) + l];
          if (sect == 0) {
            qbuf[((size_t)bh * 1024 + l) * 64 + hd] = f2bf((v + bq[jj]) * sc * 0.125f);
          } else if (sect == 1) {
            kbuf[((size_t)bh * 1024 + l) * 64 + hd] = f2bf((v + bk[jj]) * sc);
          } else {
            vT[(size_t)bh * 65536 + (size_t)hd * 1024 + l] = f2bf((v + bv[jj]) * sc);
          }
        } else {
          xout[(size_t)row * 1024 + col] = v + bo[col] + resid[(size_t)row * 1024 + col];
        }
      }
    }
  }
}

// ---------------------------------------------------------------- flash attention
// per block: one (b,h), 64 q-rows (4 waves x 16). K'=[k(64) | feat(128)], V^T staged.
__global__ __launch_bounds__(256) void k_attn(
    const unsigned short* __restrict__ qbuf, const unsigned short* __restrict__ kbuf,
    const unsigned short* __restrict__ vT, const unsigned short* __restrict__ feat,
    const float* __restrict__ maskg, unsigned short* __restrict__ ctx) {
  __shared__ __align__(16) short Kq[64 * 64];
  __shared__ __align__(16) short Kf[64 * 128];
  __shared__ __align__(16) short Vt[64 * 64];
  __shared__ float maskS[64];
  __shared__ __align__(16) short Pb[4][16 * 64];

  const int t = threadIdx.x, lane = t & 63, w = t >> 6;
  const int qt = blockIdx.x & 15, bh = blockIdx.x >> 4;
  const int b = bh >> 4, h = bh & 15;
  const int lm = lane & 15;
  const int ka = (lane >> 4) << 3;

  // preload this wave's Q'-fragments (16 rows x 192 K) into registers
  const size_t qrow = ((size_t)bh << 10) + qt * 64 + w * 16 + lm;
  short8 aq[2], af[4];
  aq[0] = *(const short8*)(qbuf + qrow * 64 + ka);
  aq[1] = *(const short8*)(qbuf + qrow * 64 + 32 + ka);
#pragma unroll
  for (int kk = 0; kk < 4; ++kk) af[kk] = *(const short8*)(feat + qrow * 128 + kk * 32 + ka);

  const f32x4 vzero = {0.f, 0.f, 0.f, 0.f};
  float m_i[4], l_i[4];
  f32x4 o[4];
#pragma unroll
  for (int r = 0; r < 4; ++r) { m_i[r] = -INFINITY; l_i[r] = 0.f; }
#pragma unroll
  for (int nt = 0; nt < 4; ++nt) o[nt] = vzero;

  const int rA = t >> 3, oA = (t & 7) << 3;   // 64x64 staging
  const int rF = t >> 4, oF = (t & 15) << 3;  // 64x128 staging

  for (int mt = 0; mt < 16; ++mt) {
    __syncthreads();
#pragma unroll
    for (int p = 0; p < 2; ++p) {
      GL16(kbuf + (((size_t)bh << 10) + mt * 64 + p * 32 + rA) * 64 + oA,
           (char*)Kq + p * 4096 + w * 1024);
      GL16(vT + ((size_t)bh << 16) + (size_t)(p * 32 + rA) * 1024 + mt * 64 + oA,
           (char*)Vt + p * 4096 + w * 1024);
    }
#pragma unroll
    for (int p = 0; p < 4; ++p) {
      GL16(feat + (((size_t)bh << 10) + mt * 64 + p * 16 + rF) * 128 + oF,
           (char*)Kf + p * 4096 + w * 1024);
    }
    if (t < 64) maskS[t] = maskg[(b << 10) + mt * 64 + t];
    __syncthreads();

    // S = Q'(16x192) . K'tile(64x192)^T
    f32x4 s[4];
#pragma unroll
    for (int nt = 0; nt < 4; ++nt) s[nt] = vzero;
#pragma unroll
    for (int nt = 0; nt < 4; ++nt) {
      const int rk = nt * 16 + lm;
      s[nt] = __builtin_amdgcn_mfma_f32_16x16x32_bf16(aq[0], *(const short8*)&Kq[rk * 64 + ka], s[nt], 0, 0, 0);
      s[nt] = __builtin_amdgcn_mfma_f32_16x16x32_bf16(aq[1], *(const short8*)&Kq[rk * 64 + 32 + ka], s[nt], 0, 0, 0);
#pragma unroll
      for (int kk = 0; kk < 4; ++kk)
        s[nt] = __builtin_amdgcn_mfma_f32_16x16x32_bf16(af[kk], *(const short8*)&Kf[rk * 128 + kk * 32 + ka], s[nt], 0, 0, 0);
    }

    // online softmax (rows live in 16-lane groups; reg r = row (lane>>4)*4+r)
    float mk[4];
#pragma unroll
    for (int nt = 0; nt < 4; ++nt) mk[nt] = maskS[nt * 16 + lm];
    float mnew[4], al[4], rsum[4];
#pragma unroll
    for (int r = 0; r < 4; ++r) {
      float v0 = fmaxf(fmaxf(s[0][r] + mk[0], s[1][r] + mk[1]),
                       fmaxf(s[2][r] + mk[2], s[3][r] + mk[3]));
#pragma unroll
      for (int m = 1; m < 16; m <<= 1) v0 = fmaxf(v0, __shfl_xor(v0, m));
      mnew[r] = fmaxf(m_i[r], v0);
      al[r] = __expf(m_i[r] - mnew[r]);
      rsum[r] = 0.f;
    }
#pragma unroll
    for (int nt = 0; nt < 4; ++nt)
#pragma unroll
      for (int r = 0; r < 4; ++r) {
        float p = __expf(s[nt][r] + mk[nt] - mnew[r]);
        s[nt][r] = p;
        rsum[r] += p;
      }
#pragma unroll
    for (int r = 0; r < 4; ++r) {
      float v0 = rsum[r];
#pragma unroll
      for (int m = 1; m < 16; m <<= 1) v0 += __shfl_xor(v0, m);
      l_i[r] = l_i[r] * al[r] + v0;
      m_i[r] = mnew[r];
    }
#pragma unroll
    for (int nt = 0; nt < 4; ++nt)
#pragma unroll
      for (int r = 0; r < 4; ++r) o[nt][r] *= al[r];

    // P (C/D layout) -> wave-private LDS -> A-fragment layout
    short* Pw = &Pb[w][0];
#pragma unroll
    for (int nt = 0; nt < 4; ++nt)
#pragma unroll
      for (int r = 0; r < 4; ++r)
        Pw[(((lane >> 4) << 2) + r) * 64 + nt * 16 + lm] = (short)f2bf(s[nt][r]);
    __syncthreads();

    // O += P(16x64) . V(64x64)   (Vt holds V^T rows = hd)
#pragma unroll
    for (int nt = 0; nt < 4; ++nt) {
      const int rv = nt * 16 + lm;
#pragma unroll
      for (int kk = 0; kk < 2; ++kk) {
        short8 ap = *(const short8*)&Pw[lm * 64 + kk * 32 + ka];
        short8 bfr = *(const short8*)&Vt[rv * 64 + kk * 32 + ka];
        o[nt] = __builtin_amdgcn_mfma_f32_16x16x32_bf16(ap, bfr, o[nt], 0, 0, 0);
      }
    }
  }

#pragma unroll
  for (int r = 0; r < 4; ++r) {
    const float inv = 1.f / l_i[r];
    const int row = (b << 10) + qt * 64 + w * 16 + ((lane >> 4) << 2) + r;
#pragma unroll
    for (int nt = 0; nt < 4; ++nt) {
      const int col = (h << 6) + nt * 16 + lm;
      ctx[(size_t)row * 1024 + col] = (short)f2bf(o[nt][r] * inv);
    }
  }
}

// ---------------------------------------------------------------- layernorm
__global__ __launch_bounds__(256) void k_ln(const float* __restrict__ x,
                                            const float* __restrict__ lw,
                                            const float* __restrict__ lb,
                                            float* __restrict__ out) {
  const int row = blockIdx.x, t = threadIdx.x, lane = t & 63, w = t >> 6;
  const float4 v = reinterpret_cast<const float4*>(x + (size_t)row * 1024)[t];
  float s = v.x + v.y + v.z + v.w;
  float s2 = v.x * v.x + v.y * v.y + v.z * v.z + v.w * v.w;
#pragma unroll
  for (int m = 1; m < 64; m <<= 1) {
    s += __shfl_xor(s, m);
    s2 += __shfl_xor(s2, m);
  }
  __shared__ float rs[4], rs2[4];
  if (lane == 0) { rs[w] = s; rs2[w] = s2; }
  __syncthreads();
  const float S = rs[0] + rs[1] + rs[2] + rs[3];
  const float S2 = rs2[0] + rs2[1] + rs2[2] + rs2[3];
  const float mu = S * (1.f / 1024.f);
  const float var = fmaxf(S2 * (1.f / 1024.f) - mu * mu, 0.f);
  const float rstd = rsqrtf(var + 1e-12f);
  const float4 wv = reinterpret_cast<const float4*>(lw)[t];
  const float4 bv = reinterpret_cast<const float4*>(lb)[t];
  float4 o;
  o.x = (v.x - mu) * rstd * wv.x + bv.x;
  o.y = (v.y - mu) * rstd * wv.y + bv.y;
  o.z = (v.z - mu) * rstd * wv.z + bv.z;
  o.w = (v.w - mu) * rstd * wv.w + bv.w;
  reinterpret_cast<float4*>(out + (size_t)row * 1024)[t] = o;
}

// ---------------------------------------------------------------- launch
extern "C" void kernel_launch(void* const* d_in, const int* in_sizes, int n_in,
                              void* d_out, int out_size, void* d_ws, size_t ws_size,
                              hipStream_t stream) {
  const float* hs = (const float*)d_in[0];
  const float* mask = (const float*)d_in[1];
  const float* cosp = (const float*)d_in[2];
  const float* sinp = (const float*)d_in[3];
  const float* mag = (const float*)d_in[4];
  const float* Wq = (const float*)d_in[5];
  const float* bq = (const float*)d_in[6];
  const float* Wk = (const float*)d_in[7];
  const float* bk = (const float*)d_in[8];
  const float* Wv = (const float*)d_in[9];
  const float* bv = (const float*)d_in[10];
  const float* Wo = (const float*)d_in[11];
  const float* bo = (const float*)d_in[12];
  const float* bl = (const float*)d_in[13];
  const float* pb = (const float*)d_in[14];
  const float* gm = (const float*)d_in[15];
  const float* lw = (const float*)d_in[16];
  const float* lbv = (const float*)d_in[17];
  float* outp = (float*)d_out;

  char* ws = (char*)d_ws;
  unsigned short* hsb  = (unsigned short*)(ws);              //  8 MB bf16 hidden
  unsigned short* wcat = (unsigned short*)(ws + 8388608);    //  6 MB bf16 [Wq;Wk;Wv]
  unsigned short* wob  = (unsigned short*)(ws + 14680064);   //  2 MB bf16 Wo
  unsigned short* qbuf = (unsigned short*)(ws + 16777216);   //  8 MB [bh][l][64]
  unsigned short* kbuf = (unsigned short*)(ws + 25165824);   //  8 MB [bh][l][64]
  unsigned short* vT   = (unsigned short*)(ws + 33554432);   //  8 MB [bh][hd][l]
  unsigned short* feat = (unsigned short*)(ws + 41943040);   // 16 MB [bh][l][128]
  unsigned short* ctx  = (unsigned short*)(ws + 58720256);   //  8 MB [row][1024]
  float* scaleB = (float*)(ws + 67108864);                   // 256 KB [bh][l]
  float* bwss   = (float*)(ws + 67371008);                   // 4 KB
  float* gpos   = (float*)(ws + 67375104);                   // 4 KB
  float* xbuf   = (float*)(ws + 16777216);                   // 16 MB, aliases q/k (dead by then)

  k_conv<<<4096, 256, 0, stream>>>(hs, hsb, 1048576);
  k_conv<<<1024, 256, 0, stream>>>(Wq, wcat, 262144);
  k_conv<<<1024, 256, 0, stream>>>(Wk, wcat + 1048576, 262144);
  k_conv<<<1024, 256, 0, stream>>>(Wv, wcat + 2097152, 262144);
  k_conv<<<1024, 256, 0, stream>>>(Wo, wob, 262144);
  k_prep_small<<<1, 64, 0, stream>>>(bl, pb, gm, bwss, gpos);
  k_prep<<<64, 256, 0, stream>>>(cosp, sinp, mag, gpos, bwss, scaleB, feat);
  k_gemm<0><<<32 * 24, 256, 0, stream>>>(hsb, wcat, 24, 1024, bq, bk, bv, scaleB,
                                         qbuf, kbuf, vT, nullptr, nullptr, nullptr);
  k_attn<<<1024, 256, 0, stream>>>(qbuf, kbuf, vT, feat, mask, ctx);
  k_gemm<1><<<32 * 8, 256, 0, stream>>>(ctx, wob, 8, 1024, nullptr, nullptr, nullptr,
                                        nullptr, nullptr, nullptr, nullptr, bo, hs, xbuf);
  k_ln<<<4096, 256, 0, stream>>>(xbuf, lw, lbv, outp);
}

// Round 2
// 232.798 us; speedup vs baseline: 1.4541x; 1.4541x over previous
//
#include <hip/hip_runtime.h>
#include <hip/hip_bf16.h>
#include <math.h>

#define DEV __device__ __forceinline__

typedef __attribute__((ext_vector_type(8))) short short8;
typedef __attribute__((ext_vector_type(8))) unsigned short ushort8v;
typedef __attribute__((ext_vector_type(4))) float f32x4;

DEV unsigned short f2bf(float f) {
  unsigned u = __float_as_uint(f);
  u = u + 0x7fffu + ((u >> 16) & 1u);
  return (unsigned short)(u >> 16);
}

DEV float softplus_f(float x) {
  return (x > 20.f) ? x : log1pf(expf(x));
}

// XOR-swizzled element addressing (16B-chunk granular, stays within the row):
// rows of 32 elems (BK=32 GEMM tiles): chunk ^= (row>>1)&3  -> 2-way (free)
DEV int sw32(int r, int e) { return r * 32 + (e ^ ((((r) >> 1) & 3) << 3)); }
// rows of 64 elems: chunk ^= row&7 -> 2-way (free)
DEV int sw64(int r, int e) { return r * 64 + (e ^ (((r) & 7) << 3)); }
// rows of 128 elems: same xor bits
DEV int sw128(int r, int e) { return r * 128 + (e ^ (((r) & 7) << 3)); }

// async global->LDS, 16B per lane. LDS dest is wave-uniform base + lane*16 (linear).
#define GL16(gp, lp) __builtin_amdgcn_global_load_lds( \
    (const __attribute__((address_space(1))) unsigned int*)(gp), \
    (__attribute__((address_space(3))) unsigned int*)(lp), 16, 0, 0)

// ---------------------------------------------------------------- conversions
__global__ __launch_bounds__(256) void k_conv(const float* __restrict__ in,
                                              unsigned short* __restrict__ out, int n4) {
  int i = blockIdx.x * 256 + threadIdx.x;
  if (i >= n4) return;
  const float4 v = reinterpret_cast<const float4*>(in)[i];
  ushort4 o;
  o.x = f2bf(v.x); o.y = f2bf(v.y); o.z = f2bf(v.z); o.w = f2bf(v.w);
  reinterpret_cast<ushort4*>(out)[i] = o;
}

// ---------------------------------------------------------------- small prep
__global__ void k_prep_small(const float* __restrict__ band_logits,
                             const float* __restrict__ phase_bias,
                             const float* __restrict__ gamma,
                             float* __restrict__ bwss, float* __restrict__ gpos) {
  const int lane = threadIdx.x;  // 64 threads, 1 wave
  for (int h = 0; h < 16; ++h) {
    float bl = band_logits[h * 64 + lane];
    float mx = bl;
#pragma unroll
    for (int m = 1; m < 64; m <<= 1) mx = fmaxf(mx, __shfl_xor(mx, m));
    float e = expf(bl - mx);
    float sm = e;
#pragma unroll
    for (int m = 1; m < 64; m <<= 1) sm += __shfl_xor(sm, m);
    float ps = softplus_f(phase_bias[h]);
    float alpha = sqrtf(ps * 0.125f);
    bwss[h * 64 + lane] = sqrtf(e / sm + 1e-8f) * alpha;
    gpos[h * 64 + lane] = softplus_f(gamma[h * 64 + lane]);
  }
}

// ---------------------------------------------------------------- scale + features
// block = (b, l-tile of 64, head-quad). 256 blocks.
__global__ __launch_bounds__(256) void k_prep(
    const float* __restrict__ cos_phi, const float* __restrict__ sin_phi,
    const float* __restrict__ mag, const float* __restrict__ gpos,
    const float* __restrict__ bwss, float* __restrict__ scaleB,
    unsigned short* __restrict__ feat) {
  const int b = blockIdx.x >> 6;
  const int l0 = ((blockIdx.x >> 2) & 15) << 6;
  const int hq = blockIdx.x & 3;
  const int t = threadIdx.x;
  __shared__ float cosL[64][65];
  __shared__ float sinL[64][65];
  __shared__ float magL[64][65];
  __shared__ float psum[4][64];
  __shared__ float minv[64];
  const size_t boff = (size_t)b * 65536;  // [B,S,L] stride
  for (int it = 0; it < 16; ++it) {
    const int s = it * 4 + (t >> 6), l = t & 63;
    const size_t g = boff + (size_t)s * 1024 + l0 + l;
    cosL[s][l] = cos_phi[g];
    sinL[s][l] = sin_phi[g];
    magL[s][l] = mag[g];
  }
  __syncthreads();
  {
    const int l = t & 63, g = t >> 6;
    float acc = 0.f;
    for (int i = 0; i < 16; ++i) acc += magL[g * 16 + i][l];
    psum[g][l] = acc;
  }
  __syncthreads();
  if (t < 64) {
    float mean = (psum[0][t] + psum[1][t] + psum[2][t] + psum[3][t]) * (1.f / 64.f);
    minv[t] = 1.f / (mean + 1e-8f);
  }
  __syncthreads();
  {
    const int l = t & 63;
    const float iv = minv[l];
    const int hidx = (hq << 2) + (t >> 6);  // one head per 64-thread group
    float acc = 0.f;
    for (int s = 0; s < 64; ++s) acc += magL[s][l] * gpos[hidx * 64 + s];
    const float tnh = tanhf(acc * iv);
    scaleB[(size_t)(((b << 4) + hidx) << 10) + l0 + l] = 1.f + 0.5f * tnh;
  }
  const int l = t >> 2, sq = (t & 3) << 4;
  for (int hh = 0; hh < 4; ++hh) {
    const int h = (hq << 2) + hh;
    unsigned short* fp = feat + ((size_t)(((b << 4) + h) << 10) + l0 + l) * 128;
    unsigned short cb[16], sb[16];
#pragma unroll
    for (int j = 0; j < 16; ++j) {
      const int s = sq + j;
      const float bw = bwss[h * 64 + s];
      cb[j] = f2bf(bw * cosL[s][l]);
      sb[j] = f2bf(bw * sinL[s][l]);
    }
    *reinterpret_cast<ushort8v*>(fp + sq) = *reinterpret_cast<ushort8v*>(cb);
    *reinterpret_cast<ushort8v*>(fp + sq + 8) = *reinterpret_cast<ushort8v*>(cb + 8);
    *reinterpret_cast<ushort8v*>(fp + 64 + sq) = *reinterpret_cast<ushort8v*>(sb);
    *reinterpret_cast<ushort8v*>(fp + 64 + sq + 8) = *reinterpret_cast<ushort8v*>(sb + 8);
  }
}

// ---------------------------------------------------------------- bf16 MFMA GEMM (B^T), 128x128 tile, BK=32
template <int MODE>
__global__ __launch_bounds__(256) void k_gemm(
    const unsigned short* __restrict__ A, const unsigned short* __restrict__ Bt,
    int Ntiles, int K,
    const float* __restrict__ bq, const float* __restrict__ bk,
    const float* __restrict__ bv, const float* __restrict__ scaleB,
    unsigned short* __restrict__ qbuf, unsigned short* __restrict__ kbuf,
    unsigned short* __restrict__ vT,
    const float* __restrict__ bo, const float* __restrict__ resid,
    float* __restrict__ xout) {
  __shared__ __align__(16) short As[128 * 32];
  __shared__ __align__(16) short Bs[128 * 32];
  const int t = threadIdx.x;
  const int lane = t & 63;
  const int w = t >> 6;
  const int tm = (blockIdx.x / Ntiles) << 7;
  const int tn = (blockIdx.x % Ntiles) << 7;
  const int wR = (w >> 1) << 6;
  const int wC = (w & 1) << 6;
  const int rowS = t >> 2;        // staging row within 64-row pass
  const int offS = (t & 3) << 3;  // staging k-offset (elements)
  const int sgm = ((rowS >> 1) & 3) << 3;  // inverse stage swizzle (row parity group)
  const int ka = (lane >> 4) << 3;
  const int lm = lane & 15;

  const f32x4 vzero = {0.f, 0.f, 0.f, 0.f};
  f32x4 acc[4][4];
#pragma unroll
  for (int i = 0; i < 4; ++i)
#pragma unroll
    for (int j = 0; j < 4; ++j) acc[i][j] = vzero;

  for (int kt = 0; kt < K; kt += 32) {
    __syncthreads();
#pragma unroll
    for (int p = 0; p < 2; ++p) {
      GL16(A + (size_t)(tm + p * 64 + rowS) * K + kt + (offS ^ sgm), (char*)As + p * 4096 + w * 1024);
      GL16(Bt + (size_t)(tn + p * 64 + rowS) * K + kt + (offS ^ sgm), (char*)Bs + p * 4096 + w * 1024);
    }
    __syncthreads();
    short8 af[4], bf[4];
#pragma unroll
    for (int mt = 0; mt < 4; ++mt) {
      const int r = wR + mt * 16 + lm;
      af[mt] = *(const short8*)&As[sw32(r, ka)];
    }
#pragma unroll
    for (int nt = 0; nt < 4; ++nt) {
      const int r = wC + nt * 16 + lm;
      bf[nt] = *(const short8*)&Bs[sw32(r, ka)];
    }
#pragma unroll
    for (int mt = 0; mt < 4; ++mt)
#pragma unroll
      for (int nt = 0; nt < 4; ++nt)
        acc[mt][nt] = __builtin_amdgcn_mfma_f32_16x16x32_bf16(af[mt], bf[nt], acc[mt][nt], 0, 0, 0);
  }

#pragma unroll
  for (int mt = 0; mt < 4; ++mt) {
#pragma unroll
    for (int r = 0; r < 4; ++r) {
      const int row = tm + wR + mt * 16 + ((lane >> 4) << 2) + r;
#pragma unroll
      for (int nt = 0; nt < 4; ++nt) {
        const int col = tn + wC + nt * 16 + lm;
        float v = acc[mt][nt][r];
        if (MODE == 0) {
          const int b = row >> 10, l = row & 1023;
          const int sect = col >> 10, jj = col & 1023;
          const int h = jj >> 6, hd = jj & 63;
          const int bh = (b << 4) + h;
          const float sc = scaleB[((size_t)bh << 10) + l];
          if (sect == 0) {
            qbuf[((size_t)bh * 1024 + l) * 64 + hd] = f2bf((v + bq[jj]) * sc * 0.125f);
          } else if (sect == 1) {
            kbuf[((size_t)bh * 1024 + l) * 64 + hd] = f2bf((v + bk[jj]) * sc);
          } else {
            vT[(size_t)bh * 65536 + (size_t)hd * 1024 + l] = f2bf((v + bv[jj]) * sc);
          }
        } else {
          xout[(size_t)row * 1024 + col] = v + bo[col] + resid[(size_t)row * 1024 + col];
        }
      }
    }
  }
}

// ---------------------------------------------------------------- flash attention
// per block: one (b,h), 64 q-rows (4 waves x 16). K'=[k(64) | feat(128)], V^T staged.
// LDS: Kq(8K, P aliases it after QK) + Kf(16K) + Vt(8K) + mask(4K) = 36.9KB -> 4 blocks/CU.
__global__ __launch_bounds__(256) void k_attn(
    const unsigned short* __restrict__ qbuf, const unsigned short* __restrict__ kbuf,
    const unsigned short* __restrict__ vT, const unsigned short* __restrict__ feat,
    const float* __restrict__ maskg, unsigned short* __restrict__ ctx) {
  __shared__ __align__(16) short Kq[64 * 64];
  __shared__ __align__(16) short Kf[64 * 128];
  __shared__ __align__(16) short Vt[64 * 64];
  __shared__ float maskAll[1024];

  const int t = threadIdx.x, lane = t & 63, w = t >> 6;
  const int qt = blockIdx.x & 15, bh = blockIdx.x >> 4;
  const int b = bh >> 4, h = bh & 15;
  const int lm = lane & 15;
  const int ka = (lane >> 4) << 3;

  // whole-row mask for this batch, staged once
  for (int i = t; i < 1024; i += 256) maskAll[i] = maskg[(b << 10) + i];

  // preload this wave's Q'-fragments (16 rows x 192 K) into registers
  const size_t qrow = ((size_t)bh << 10) + qt * 64 + w * 16 + lm;
  short8 aq[2], af[4];
  aq[0] = *(const short8*)(qbuf + qrow * 64 + ka);
  aq[1] = *(const short8*)(qbuf + qrow * 64 + 32 + ka);
#pragma unroll
  for (int kk = 0; kk < 4; ++kk) af[kk] = *(const short8*)(feat + qrow * 128 + kk * 32 + ka);

  const f32x4 vzero = {0.f, 0.f, 0.f, 0.f};
  float m_i[4], l_i[4];
  f32x4 o[4];
#pragma unroll
  for (int r = 0; r < 4; ++r) { m_i[r] = -INFINITY; l_i[r] = 0.f; }
#pragma unroll
  for (int nt = 0; nt < 4; ++nt) o[nt] = vzero;

  const int rA = t >> 3, oA = (t & 7) << 3;   // 64x64 staging
  const int rF = t >> 4, oF = (t & 15) << 3;  // 64x128 staging
  const int swA = (rA & 7) << 3;              // inverse stage swizzle (element units)
  const int swF = (rF & 7) << 3;

  for (int mt = 0; mt < 16; ++mt) {
    __syncthreads();  // prev tile's LDS reads (incl. P in Kq region) done
#pragma unroll
    for (int p = 0; p < 2; ++p) {
      GL16(kbuf + (((size_t)bh << 10) + mt * 64 + p * 32 + rA) * 64 + (oA ^ swA),
           (char*)Kq + p * 4096 + w * 1024);
      GL16(vT + ((size_t)bh << 16) + (size_t)(p * 32 + rA) * 1024 + mt * 64 + (oA ^ swA),
           (char*)Vt + p * 4096 + w * 1024);
    }
#pragma unroll
    for (int p = 0; p < 4; ++p) {
      GL16(feat + (((size_t)bh << 10) + mt * 64 + p * 16 + rF) * 128 + (oF ^ swF),
           (char*)Kf + p * 4096 + w * 1024);
    }
    __syncthreads();  // staging complete

    // S = Q'(16x192) . K'tile(64x192)^T   (swizzled LDS reads: 2-way max)
    f32x4 s[4];
#pragma unroll
    for (int nt = 0; nt < 4; ++nt) s[nt] = vzero;
#pragma unroll
    for (int nt = 0; nt < 4; ++nt) {
      const int rk = nt * 16 + lm;
      s[nt] = __builtin_amdgcn_mfma_f32_16x16x32_bf16(aq[0], *(const short8*)&Kq[sw64(rk, ka)], s[nt], 0, 0, 0);
      s[nt] = __builtin_amdgcn_mfma_f32_16x16x32_bf16(aq[1], *(const short8*)&Kq[sw64(rk, 32 + ka)], s[nt], 0, 0, 0);
#pragma unroll
      for (int kk = 0; kk < 4; ++kk)
        s[nt] = __builtin_amdgcn_mfma_f32_16x16x32_bf16(af[kk], *(const short8*)&Kf[sw128(rk, kk * 32 + ka)], s[nt], 0, 0, 0);
    }

    // online softmax (rows live in 16-lane groups; reg r = row (lane>>4)*4+r)
    float mk[4];
#pragma unroll
    for (int nt = 0; nt < 4; ++nt) mk[nt] = maskAll[mt * 64 + nt * 16 + lm];
    float mnew[4], al[4], rsum[4];
#pragma unroll
    for (int r = 0; r < 4; ++r) {
      float v0 = fmaxf(fmaxf(s[0][r] + mk[0], s[1][r] + mk[1]),
                       fmaxf(s[2][r] + mk[2], s[3][r] + mk[3]));
#pragma unroll
      for (int m = 1; m < 16; m <<= 1) v0 = fmaxf(v0, __shfl_xor(v0, m));
      mnew[r] = fmaxf(m_i[r], v0);
      al[r] = __expf(m_i[r] - mnew[r]);
      rsum[r] = 0.f;
    }
#pragma unroll
    for (int nt = 0; nt < 4; ++nt)
#pragma unroll
      for (int r = 0; r < 4; ++r) {
        float p = __expf(s[nt][r] + mk[nt] - mnew[r]);
        s[nt][r] = p;
        rsum[r] += p;
      }
#pragma unroll
    for (int r = 0; r < 4; ++r) {
      float v0 = rsum[r];
#pragma unroll
      for (int m = 1; m < 16; m <<= 1) v0 += __shfl_xor(v0, m);
      l_i[r] = l_i[r] * al[r] + v0;
      m_i[r] = mnew[r];
    }
#pragma unroll
    for (int nt = 0; nt < 4; ++nt)
#pragma unroll
      for (int r = 0; r < 4; ++r) o[nt][r] *= al[r];

    __syncthreads();  // all waves done with Kq (QK reads) before P overwrites it

    // P (C/D layout) -> wave-private window aliased onto Kq, swizzled
    short* Pw = (short*)Kq + (w << 10);
#pragma unroll
    for (int nt = 0; nt < 4; ++nt)
#pragma unroll
      for (int r = 0; r < 4; ++r) {
        const int prow = ((lane >> 4) << 2) + r;
        Pw[sw64(prow, nt * 16 + lm)] = (short)f2bf(s[nt][r]);
      }

    // O += P(16x64) . V(64x64)   (Vt holds V^T rows = hd)
#pragma unroll
    for (int nt = 0; nt < 4; ++nt) {
      const int rv = nt * 16 + lm;
#pragma unroll
      for (int kk = 0; kk < 2; ++kk) {
        short8 ap = *(const short8*)&Pw[sw64(lm, kk * 32 + ka)];
        short8 bfr = *(const short8*)&Vt[sw64(rv, kk * 32 + ka)];
        o[nt] = __builtin_amdgcn_mfma_f32_16x16x32_bf16(ap, bfr, o[nt], 0, 0, 0);
      }
    }
  }

#pragma unroll
  for (int r = 0; r < 4; ++r) {
    const float inv = 1.f / l_i[r];
    const int row = (b << 10) + qt * 64 + w * 16 + ((lane >> 4) << 2) + r;
#pragma unroll
    for (int nt = 0; nt < 4; ++nt) {
      const int col = (h << 6) + nt * 16 + lm;
      ctx[(size_t)row * 1024 + col] = (short)f2bf(o[nt][r] * inv);
    }
  }
}

// ---------------------------------------------------------------- layernorm
__global__ __launch_bounds__(256) void k_ln(const float* __restrict__ x,
                                            const float* __restrict__ lw,
                                            const float* __restrict__ lb,
                                            float* __restrict__ out) {
  const int row = blockIdx.x, t = threadIdx.x, lane = t & 63, w = t >> 6;
  const float4 v = reinterpret_cast<const float4*>(x + (size_t)row * 1024)[t];
  float s = v.x + v.y + v.z + v.w;
  float s2 = v.x * v.x + v.y * v.y + v.z * v.z + v.w * v.w;
#pragma unroll
  for (int m = 1; m < 64; m <<= 1) {
    s += __shfl_xor(s, m);
    s2 += __shfl_xor(s2, m);
  }
  __shared__ float rs[4], rs2[4];
  if (lane == 0) { rs[w] = s; rs2[w] = s2; }
  __syncthreads();
  const float S = rs[0] + rs[1] + rs[2] + rs[3];
  const float S2 = rs2[0] + rs2[1] + rs2[2] + rs2[3];
  const float mu = S * (1.f / 1024.f);
  const float var = fmaxf(S2 * (1.f / 1024.f) - mu * mu, 0.f);
  const float rstd = rsqrtf(var + 1e-12f);
  const float4 wv = reinterpret_cast<const float4*>(lw)[t];
  const float4 bv = reinterpret_cast<const float4*>(lb)[t];
  float4 o;
  o.x = (v.x - mu) * rstd * wv.x + bv.x;
  o.y = (v.y - mu) * rstd * wv.y + bv.y;
  o.z = (v.z - mu) * rstd * wv.z + bv.z;
  o.w = (v.w - mu) * rstd * wv.w + bv.w;
  reinterpret_cast<float4*>(out + (size_t)row * 1024)[t] = o;
}

// ---------------------------------------------------------------- launch
extern "C" void kernel_launch(void* const* d_in, const int* in_sizes, int n_in,
                              void* d_out, int out_size, void* d_ws, size_t ws_size,
                              hipStream_t stream) {
  const float* hs = (const float*)d_in[0];
  const float* mask = (const float*)d_in[1];
  const float* cosp = (const float*)d_in[2];
  const float* sinp = (const float*)d_in[3];
  const float* mag = (const float*)d_in[4];
  const float* Wq = (const float*)d_in[5];
  const float* bq = (const float*)d_in[6];
  const float* Wk = (const float*)d_in[7];
  const float* bk = (const float*)d_in[8];
  const float* Wv = (const float*)d_in[9];
  const float* bv = (const float*)d_in[10];
  const float* Wo = (const float*)d_in[11];
  const float* bo = (const float*)d_in[12];
  const float* bl = (const float*)d_in[13];
  const float* pb = (const float*)d_in[14];
  const float* gm = (const float*)d_in[15];
  const float* lw = (const float*)d_in[16];
  const float* lbv = (const float*)d_in[17];
  float* outp = (float*)d_out;

  char* ws = (char*)d_ws;
  unsigned short* hsb  = (unsigned short*)(ws);              //  8 MB bf16 hidden
  unsigned short* wcat = (unsigned short*)(ws + 8388608);    //  6 MB bf16 [Wq;Wk;Wv]
  unsigned short* wob  = (unsigned short*)(ws + 14680064);   //  2 MB bf16 Wo
  unsigned short* qbuf = (unsigned short*)(ws + 16777216);   //  8 MB [bh][l][64]
  unsigned short* kbuf = (unsigned short*)(ws + 25165824);   //  8 MB [bh][l][64]
  unsigned short* vT   = (unsigned short*)(ws + 33554432);   //  8 MB [bh][hd][l]
  unsigned short* feat = (unsigned short*)(ws + 41943040);   // 16 MB [bh][l][128]
  unsigned short* ctx  = (unsigned short*)(ws + 58720256);   //  8 MB [row][1024]
  float* scaleB = (float*)(ws + 67108864);                   // 256 KB [bh][l]
  float* bwss   = (float*)(ws + 67371008);                   // 4 KB
  float* gpos   = (float*)(ws + 67375104);                   // 4 KB
  float* xbuf   = (float*)(ws + 16777216);                   // 16 MB, aliases q/k (dead by then)

  k_conv<<<4096, 256, 0, stream>>>(hs, hsb, 1048576);
  k_conv<<<1024, 256, 0, stream>>>(Wq, wcat, 262144);
  k_conv<<<1024, 256, 0, stream>>>(Wk, wcat + 1048576, 262144);
  k_conv<<<1024, 256, 0, stream>>>(Wv, wcat + 2097152, 262144);
  k_conv<<<1024, 256, 0, stream>>>(Wo, wob, 262144);
  k_prep_small<<<1, 64, 0, stream>>>(bl, pb, gm, bwss, gpos);
  k_prep<<<256, 256, 0, stream>>>(cosp, sinp, mag, gpos, bwss, scaleB, feat);
  k_gemm<0><<<32 * 24, 256, 0, stream>>>(hsb, wcat, 24, 1024, bq, bk, bv, scaleB,
                                         qbuf, kbuf, vT, nullptr, nullptr, nullptr);
  k_attn<<<1024, 256, 0, stream>>>(qbuf, kbuf, vT, feat, mask, ctx);
  k_gemm<1><<<32 * 8, 256, 0, stream>>>(ctx, wob, 8, 1024, nullptr, nullptr, nullptr,
                                        nullptr, nullptr, nullptr, nullptr, bo, hs, xbuf);
  k_ln<<<4096, 256, 0, stream>>>(xbuf, lw, lbv, outp);
}

// Round 3
// 228.352 us; speedup vs baseline: 1.4824x; 1.0195x over previous
//
#include <hip/hip_runtime.h>
#include <hip/hip_bf16.h>
#include <math.h>

#define DEV __device__ __forceinline__

typedef __attribute__((ext_vector_type(8))) short short8;
typedef __attribute__((ext_vector_type(8))) unsigned short ushort8v;
typedef __attribute__((ext_vector_type(4))) float f32x4;

DEV unsigned short f2bf(float f) {
  unsigned u = __float_as_uint(f);
  u = u + 0x7fffu + ((u >> 16) & 1u);
  return (unsigned short)(u >> 16);
}

DEV float softplus_f(float x) {
  return (x > 20.f) ? x : log1pf(expf(x));
}

// XOR-swizzled element addressing (16B-chunk granular, stays within the row):
DEV int sw32(int r, int e) { return r * 32 + (e ^ ((((r) >> 1) & 3) << 3)); }
DEV int sw64(int r, int e) { return r * 64 + (e ^ (((r) & 7) << 3)); }
DEV int sw128(int r, int e) { return r * 128 + (e ^ (((r) & 7) << 3)); }

// async global->LDS, 16B per lane. LDS dest is wave-uniform base + lane*16 (linear).
#define GL16(gp, lp) __builtin_amdgcn_global_load_lds( \
    (const __attribute__((address_space(1))) unsigned int*)(gp), \
    (__attribute__((address_space(3))) unsigned int*)(lp), 16, 0, 0)

// ---------------------------------------------------------------- conversions
__global__ __launch_bounds__(256) void k_conv(const float* __restrict__ in,
                                              unsigned short* __restrict__ out, int n4) {
  int i = blockIdx.x * 256 + threadIdx.x;
  if (i >= n4) return;
  const float4 v = reinterpret_cast<const float4*>(in)[i];
  ushort4 o;
  o.x = f2bf(v.x); o.y = f2bf(v.y); o.z = f2bf(v.z); o.w = f2bf(v.w);
  reinterpret_cast<ushort4*>(out)[i] = o;
}

// ---------------------------------------------------------------- small prep
__global__ void k_prep_small(const float* __restrict__ band_logits,
                             const float* __restrict__ phase_bias,
                             const float* __restrict__ gamma,
                             float* __restrict__ bwss, float* __restrict__ gpos) {
  const int lane = threadIdx.x;  // 64 threads, 1 wave
  for (int h = 0; h < 16; ++h) {
    float bl = band_logits[h * 64 + lane];
    float mx = bl;
#pragma unroll
    for (int m = 1; m < 64; m <<= 1) mx = fmaxf(mx, __shfl_xor(mx, m));
    float e = expf(bl - mx);
    float sm = e;
#pragma unroll
    for (int m = 1; m < 64; m <<= 1) sm += __shfl_xor(sm, m);
    float ps = softplus_f(phase_bias[h]);
    float alpha = sqrtf(ps * 0.125f);
    bwss[h * 64 + lane] = sqrtf(e / sm + 1e-8f) * alpha;
    gpos[h * 64 + lane] = softplus_f(gamma[h * 64 + lane]);
  }
}

// ---------------------------------------------------------------- scale + features
__global__ __launch_bounds__(256) void k_prep(
    const float* __restrict__ cos_phi, const float* __restrict__ sin_phi,
    const float* __restrict__ mag, const float* __restrict__ gpos,
    const float* __restrict__ bwss, float* __restrict__ scaleB,
    unsigned short* __restrict__ feat) {
  const int b = blockIdx.x >> 6;
  const int l0 = ((blockIdx.x >> 2) & 15) << 6;
  const int hq = blockIdx.x & 3;
  const int t = threadIdx.x;
  __shared__ float cosL[64][65];
  __shared__ float sinL[64][65];
  __shared__ float magL[64][65];
  __shared__ float psum[4][64];
  __shared__ float minv[64];
  const size_t boff = (size_t)b * 65536;  // [B,S,L] stride
  for (int it = 0; it < 16; ++it) {
    const int s = it * 4 + (t >> 6), l = t & 63;
    const size_t g = boff + (size_t)s * 1024 + l0 + l;
    cosL[s][l] = cos_phi[g];
    sinL[s][l] = sin_phi[g];
    magL[s][l] = mag[g];
  }
  __syncthreads();
  {
    const int l = t & 63, g = t >> 6;
    float acc = 0.f;
    for (int i = 0; i < 16; ++i) acc += magL[g * 16 + i][l];
    psum[g][l] = acc;
  }
  __syncthreads();
  if (t < 64) {
    float mean = (psum[0][t] + psum[1][t] + psum[2][t] + psum[3][t]) * (1.f / 64.f);
    minv[t] = 1.f / (mean + 1e-8f);
  }
  __syncthreads();
  {
    const int l = t & 63;
    const float iv = minv[l];
    const int hidx = (hq << 2) + (t >> 6);  // one head per 64-thread group
    float acc = 0.f;
    for (int s = 0; s < 64; ++s) acc += magL[s][l] * gpos[hidx * 64 + s];
    const float tnh = tanhf(acc * iv);
    scaleB[(size_t)(((b << 4) + hidx) << 10) + l0 + l] = 1.f + 0.5f * tnh;
  }
  const int l = t >> 2, sq = (t & 3) << 4;
  for (int hh = 0; hh < 4; ++hh) {
    const int h = (hq << 2) + hh;
    unsigned short* fp = feat + ((size_t)(((b << 4) + h) << 10) + l0 + l) * 128;
    unsigned short cb[16], sb[16];
#pragma unroll
    for (int j = 0; j < 16; ++j) {
      const int s = sq + j;
      const float bw = bwss[h * 64 + s];
      cb[j] = f2bf(bw * cosL[s][l]);
      sb[j] = f2bf(bw * sinL[s][l]);
    }
    *reinterpret_cast<ushort8v*>(fp + sq) = *reinterpret_cast<ushort8v*>(cb);
    *reinterpret_cast<ushort8v*>(fp + sq + 8) = *reinterpret_cast<ushort8v*>(cb + 8);
    *reinterpret_cast<ushort8v*>(fp + 64 + sq) = *reinterpret_cast<ushort8v*>(sb);
    *reinterpret_cast<ushort8v*>(fp + 64 + sq + 8) = *reinterpret_cast<ushort8v*>(sb + 8);
  }
}

// ---------------------------------------------------------------- bf16 MFMA GEMM (B^T), 128x128 tile, BK=32
template <int MODE>
__global__ __launch_bounds__(256) void k_gemm(
    const unsigned short* __restrict__ A, const unsigned short* __restrict__ Bt,
    int Ntiles, int K,
    const float* __restrict__ bq, const float* __restrict__ bk,
    const float* __restrict__ bv, const float* __restrict__ scaleB,
    unsigned short* __restrict__ qbuf, unsigned short* __restrict__ kbuf,
    unsigned short* __restrict__ vT,
    const float* __restrict__ bo, const float* __restrict__ resid,
    float* __restrict__ xout) {
  __shared__ __align__(16) short As[128 * 32];
  __shared__ __align__(16) short Bs[128 * 32];
  const int t = threadIdx.x;
  const int lane = t & 63;
  const int w = t >> 6;
  const int tm = (blockIdx.x / Ntiles) << 7;
  const int tn = (blockIdx.x % Ntiles) << 7;
  const int wR = (w >> 1) << 6;
  const int wC = (w & 1) << 6;
  const int rowS = t >> 2;        // staging row within 64-row pass
  const int offS = (t & 3) << 3;  // staging k-offset (elements)
  const int sgm = ((rowS >> 1) & 3) << 3;  // inverse stage swizzle
  const int ka = (lane >> 4) << 3;
  const int lm = lane & 15;

  const f32x4 vzero = {0.f, 0.f, 0.f, 0.f};
  f32x4 acc[4][4];
#pragma unroll
  for (int i = 0; i < 4; ++i)
#pragma unroll
    for (int j = 0; j < 4; ++j) acc[i][j] = vzero;

  for (int kt = 0; kt < K; kt += 32) {
    __syncthreads();
#pragma unroll
    for (int p = 0; p < 2; ++p) {
      GL16(A + (size_t)(tm + p * 64 + rowS) * K + kt + (offS ^ sgm), (char*)As + p * 4096 + w * 1024);
      GL16(Bt + (size_t)(tn + p * 64 + rowS) * K + kt + (offS ^ sgm), (char*)Bs + p * 4096 + w * 1024);
    }
    __syncthreads();
    short8 af[4], bf[4];
#pragma unroll
    for (int mt = 0; mt < 4; ++mt) {
      const int r = wR + mt * 16 + lm;
      af[mt] = *(const short8*)&As[sw32(r, ka)];
    }
#pragma unroll
    for (int nt = 0; nt < 4; ++nt) {
      const int r = wC + nt * 16 + lm;
      bf[nt] = *(const short8*)&Bs[sw32(r, ka)];
    }
#pragma unroll
    for (int mt = 0; mt < 4; ++mt)
#pragma unroll
      for (int nt = 0; nt < 4; ++nt)
        acc[mt][nt] = __builtin_amdgcn_mfma_f32_16x16x32_bf16(af[mt], bf[nt], acc[mt][nt], 0, 0, 0);
  }

#pragma unroll
  for (int mt = 0; mt < 4; ++mt) {
#pragma unroll
    for (int r = 0; r < 4; ++r) {
      const int row = tm + wR + mt * 16 + ((lane >> 4) << 2) + r;
#pragma unroll
      for (int nt = 0; nt < 4; ++nt) {
        const int col = tn + wC + nt * 16 + lm;
        float v = acc[mt][nt][r];
        if (MODE == 0) {
          const int b = row >> 10, l = row & 1023;
          const int sect = col >> 10, jj = col & 1023;
          const int h = jj >> 6, hd = jj & 63;
          const int bh = (b << 4) + h;
          const float sc = scaleB[((size_t)bh << 10) + l];
          if (sect == 0) {
            qbuf[((size_t)bh * 1024 + l) * 64 + hd] = f2bf((v + bq[jj]) * sc * 0.125f);
          } else if (sect == 1) {
            kbuf[((size_t)bh * 1024 + l) * 64 + hd] = f2bf((v + bk[jj]) * sc);
          } else {
            vT[(size_t)bh * 65536 + (size_t)hd * 1024 + l] = f2bf((v + bv[jj]) * sc);
          }
        } else {
          xout[(size_t)row * 1024 + col] = v + bo[col] + resid[(size_t)row * 1024 + col];
        }
      }
    }
  }
}

// ---------------------------------------------------------------- flash attention
// per block: one (b,h), 64 q-rows (4 waves x 16). K'=[k(64) | feat(128)], V^T staged.
// Double-buffered LDS prefetch (2-phase): Kq 16K + Kf 32K + Vt 16K + Pb 8K + mask 4K = 76KB.
// blockIdx remap: bh = blockIdx & 63 -> all 16 q-tiles of one bh land on one XCD (L2 reuse).
__global__ __launch_bounds__(256) void k_attn(
    const unsigned short* __restrict__ qbuf, const unsigned short* __restrict__ kbuf,
    const unsigned short* __restrict__ vT, const unsigned short* __restrict__ feat,
    const float* __restrict__ maskg, unsigned short* __restrict__ ctx) {
  __shared__ __align__(16) short Kq[2][64 * 64];
  __shared__ __align__(16) short Kf[2][64 * 128];
  __shared__ __align__(16) short Vt[2][64 * 64];
  __shared__ __align__(16) short Pb[4][16 * 64];
  __shared__ float maskAll[1024];

  const int t = threadIdx.x, lane = t & 63, w = t >> 6;
  const int bh = blockIdx.x & 63;   // consecutive ids span bh -> same-bh blocks differ by 64 -> same XCD
  const int qt = blockIdx.x >> 6;
  const int b = bh >> 4, h = bh & 15;
  const int lm = lane & 15;
  const int ka = (lane >> 4) << 3;

  // whole-row mask for this batch, staged once
  for (int i = t; i < 1024; i += 256) maskAll[i] = maskg[(b << 10) + i];

  // preload this wave's Q'-fragments (16 rows x 192 K) into registers
  const size_t qrow = ((size_t)bh << 10) + qt * 64 + w * 16 + lm;
  short8 aq[2], af[4];
  aq[0] = *(const short8*)(qbuf + qrow * 64 + ka);
  aq[1] = *(const short8*)(qbuf + qrow * 64 + 32 + ka);
#pragma unroll
  for (int kk = 0; kk < 4; ++kk) af[kk] = *(const short8*)(feat + qrow * 128 + kk * 32 + ka);

  const f32x4 vzero = {0.f, 0.f, 0.f, 0.f};
  float m_i[4], l_i[4];
  f32x4 o[4];
#pragma unroll
  for (int r = 0; r < 4; ++r) { m_i[r] = -INFINITY; l_i[r] = 0.f; }
#pragma unroll
  for (int nt = 0; nt < 4; ++nt) o[nt] = vzero;

  const int rA = t >> 3, oA = (t & 7) << 3;   // 64x64 staging
  const int rF = t >> 4, oF = (t & 15) << 3;  // 64x128 staging
  const int swA = (rA & 7) << 3;              // inverse stage swizzle (element units)
  const int swF = (rF & 7) << 3;

#define STAGE(mt_, d_) do {                                                           \
    _Pragma("unroll")                                                                 \
    for (int p = 0; p < 2; ++p) {                                                     \
      GL16(kbuf + (((size_t)bh << 10) + (mt_) * 64 + p * 32 + rA) * 64 + (oA ^ swA),  \
           (char*)&Kq[d_][0] + p * 4096 + w * 1024);                                  \
      GL16(vT + ((size_t)bh << 16) + (size_t)(p * 32 + rA) * 1024 + (mt_) * 64 + (oA ^ swA), \
           (char*)&Vt[d_][0] + p * 4096 + w * 1024);                                  \
    }                                                                                 \
    _Pragma("unroll")                                                                 \
    for (int p = 0; p < 4; ++p) {                                                     \
      GL16(feat + (((size_t)bh << 10) + (mt_) * 64 + p * 16 + rF) * 128 + (oF ^ swF), \
           (char*)&Kf[d_][0] + p * 4096 + w * 1024);                                  \
    }                                                                                 \
  } while (0)

  STAGE(0, 0);
  __syncthreads();  // prologue stage complete (implicit vmcnt(0))

  for (int mt = 0; mt < 16; ++mt) {
    const int cur = mt & 1;
    if (mt < 15) STAGE(mt + 1, cur ^ 1);  // prefetch next tile; overlaps compute below
    const short* KqC = &Kq[cur][0];
    const short* KfC = &Kf[cur][0];
    const short* VtC = &Vt[cur][0];

    // S = Q'(16x192) . K'tile(64x192)^T   (swizzled LDS reads: 2-way max)
    f32x4 s[4];
#pragma unroll
    for (int nt = 0; nt < 4; ++nt) s[nt] = vzero;
#pragma unroll
    for (int nt = 0; nt < 4; ++nt) {
      const int rk = nt * 16 + lm;
      s[nt] = __builtin_amdgcn_mfma_f32_16x16x32_bf16(aq[0], *(const short8*)&KqC[sw64(rk, ka)], s[nt], 0, 0, 0);
      s[nt] = __builtin_amdgcn_mfma_f32_16x16x32_bf16(aq[1], *(const short8*)&KqC[sw64(rk, 32 + ka)], s[nt], 0, 0, 0);
#pragma unroll
      for (int kk = 0; kk < 4; ++kk)
        s[nt] = __builtin_amdgcn_mfma_f32_16x16x32_bf16(af[kk], *(const short8*)&KfC[sw128(rk, kk * 32 + ka)], s[nt], 0, 0, 0);
    }

    // online softmax (rows live in 16-lane groups; reg r = row (lane>>4)*4+r)
    float mk[4];
#pragma unroll
    for (int nt = 0; nt < 4; ++nt) mk[nt] = maskAll[mt * 64 + nt * 16 + lm];
    float mnew[4], al[4], rsum[4];
#pragma unroll
    for (int r = 0; r < 4; ++r) {
      float v0 = fmaxf(fmaxf(s[0][r] + mk[0], s[1][r] + mk[1]),
                       fmaxf(s[2][r] + mk[2], s[3][r] + mk[3]));
#pragma unroll
      for (int m = 1; m < 16; m <<= 1) v0 = fmaxf(v0, __shfl_xor(v0, m));
      mnew[r] = fmaxf(m_i[r], v0);
      al[r] = __expf(m_i[r] - mnew[r]);
      rsum[r] = 0.f;
    }
#pragma unroll
    for (int nt = 0; nt < 4; ++nt)
#pragma unroll
      for (int r = 0; r < 4; ++r) {
        float p = __expf(s[nt][r] + mk[nt] - mnew[r]);
        s[nt][r] = p;
        rsum[r] += p;
      }
#pragma unroll
    for (int r = 0; r < 4; ++r) {
      float v0 = rsum[r];
#pragma unroll
      for (int m = 1; m < 16; m <<= 1) v0 += __shfl_xor(v0, m);
      l_i[r] = l_i[r] * al[r] + v0;
      m_i[r] = mnew[r];
    }
#pragma unroll
    for (int nt = 0; nt < 4; ++nt)
#pragma unroll
      for (int r = 0; r < 4; ++r) o[nt][r] *= al[r];

    // P (C/D layout) -> wave-private Pb (no barrier needed: within-wave LDS dep)
    short* Pw = &Pb[w][0];
#pragma unroll
    for (int nt = 0; nt < 4; ++nt)
#pragma unroll
      for (int r = 0; r < 4; ++r) {
        const int prow = ((lane >> 4) << 2) + r;
        Pw[sw64(prow, nt * 16 + lm)] = (short)f2bf(s[nt][r]);
      }

    // O += P(16x64) . V(64x64)   (Vt holds V^T rows = hd)
#pragma unroll
    for (int nt = 0; nt < 4; ++nt) {
      const int rv = nt * 16 + lm;
#pragma unroll
      for (int kk = 0; kk < 2; ++kk) {
        short8 ap = *(const short8*)&Pw[sw64(lm, kk * 32 + ka)];
        short8 bfr = *(const short8*)&VtC[sw64(rv, kk * 32 + ka)];
        o[nt] = __builtin_amdgcn_mfma_f32_16x16x32_bf16(ap, bfr, o[nt], 0, 0, 0);
      }
    }

    __syncthreads();  // all waves done reading buf[cur]; prefetch (vmcnt) drained
  }
#undef STAGE

#pragma unroll
  for (int r = 0; r < 4; ++r) {
    const float inv = 1.f / l_i[r];
    const int row = (b << 10) + qt * 64 + w * 16 + ((lane >> 4) << 2) + r;
#pragma unroll
    for (int nt = 0; nt < 4; ++nt) {
      const int col = (h << 6) + nt * 16 + lm;
      ctx[(size_t)row * 1024 + col] = (short)f2bf(o[nt][r] * inv);
    }
  }
}

// ---------------------------------------------------------------- layernorm
__global__ __launch_bounds__(256) void k_ln(const float* __restrict__ x,
                                            const float* __restrict__ lw,
                                            const float* __restrict__ lb,
                                            float* __restrict__ out) {
  const int row = blockIdx.x, t = threadIdx.x, lane = t & 63, w = t >> 6;
  const float4 v = reinterpret_cast<const float4*>(x + (size_t)row * 1024)[t];
  float s = v.x + v.y + v.z + v.w;
  float s2 = v.x * v.x + v.y * v.y + v.z * v.z + v.w * v.w;
#pragma unroll
  for (int m = 1; m < 64; m <<= 1) {
    s += __shfl_xor(s, m);
    s2 += __shfl_xor(s2, m);
  }
  __shared__ float rs[4], rs2[4];
  if (lane == 0) { rs[w] = s; rs2[w] = s2; }
  __syncthreads();
  const float S = rs[0] + rs[1] + rs[2] + rs[3];
  const float S2 = rs2[0] + rs2[1] + rs2[2] + rs2[3];
  const float mu = S * (1.f / 1024.f);
  const float var = fmaxf(S2 * (1.f / 1024.f) - mu * mu, 0.f);
  const float rstd = rsqrtf(var + 1e-12f);
  const float4 wv = reinterpret_cast<const float4*>(lw)[t];
  const float4 bv = reinterpret_cast<const float4*>(lb)[t];
  float4 o;
  o.x = (v.x - mu) * rstd * wv.x + bv.x;
  o.y = (v.y - mu) * rstd * wv.y + bv.y;
  o.z = (v.z - mu) * rstd * wv.z + bv.z;
  o.w = (v.w - mu) * rstd * wv.w + bv.w;
  reinterpret_cast<float4*>(out + (size_t)row * 1024)[t] = o;
}

// ---------------------------------------------------------------- launch
extern "C" void kernel_launch(void* const* d_in, const int* in_sizes, int n_in,
                              void* d_out, int out_size, void* d_ws, size_t ws_size,
                              hipStream_t stream) {
  const float* hs = (const float*)d_in[0];
  const float* mask = (const float*)d_in[1];
  const float* cosp = (const float*)d_in[2];
  const float* sinp = (const float*)d_in[3];
  const float* mag = (const float*)d_in[4];
  const float* Wq = (const float*)d_in[5];
  const float* bq = (const float*)d_in[6];
  const float* Wk = (const float*)d_in[7];
  const float* bk = (const float*)d_in[8];
  const float* Wv = (const float*)d_in[9];
  const float* bv = (const float*)d_in[10];
  const float* Wo = (const float*)d_in[11];
  const float* bo = (const float*)d_in[12];
  const float* bl = (const float*)d_in[13];
  const float* pb = (const float*)d_in[14];
  const float* gm = (const float*)d_in[15];
  const float* lw = (const float*)d_in[16];
  const float* lbv = (const float*)d_in[17];
  float* outp = (float*)d_out;

  char* ws = (char*)d_ws;
  unsigned short* hsb  = (unsigned short*)(ws);              //  8 MB bf16 hidden
  unsigned short* wcat = (unsigned short*)(ws + 8388608);    //  6 MB bf16 [Wq;Wk;Wv]
  unsigned short* wob  = (unsigned short*)(ws + 14680064);   //  2 MB bf16 Wo
  unsigned short* qbuf = (unsigned short*)(ws + 16777216);   //  8 MB [bh][l][64]
  unsigned short* kbuf = (unsigned short*)(ws + 25165824);   //  8 MB [bh][l][64]
  unsigned short* vT   = (unsigned short*)(ws + 33554432);   //  8 MB [bh][hd][l]
  unsigned short* feat = (unsigned short*)(ws + 41943040);   // 16 MB [bh][l][128]
  unsigned short* ctx  = (unsigned short*)(ws + 58720256);   //  8 MB [row][1024]
  float* scaleB = (float*)(ws + 67108864);                   // 256 KB [bh][l]
  float* bwss   = (float*)(ws + 67371008);                   // 4 KB
  float* gpos   = (float*)(ws + 67375104);                   // 4 KB
  float* xbuf   = (float*)(ws + 16777216);                   // 16 MB, aliases q/k (dead by then)

  k_conv<<<4096, 256, 0, stream>>>(hs, hsb, 1048576);
  k_conv<<<1024, 256, 0, stream>>>(Wq, wcat, 262144);
  k_conv<<<1024, 256, 0, stream>>>(Wk, wcat + 1048576, 262144);
  k_conv<<<1024, 256, 0, stream>>>(Wv, wcat + 2097152, 262144);
  k_conv<<<1024, 256, 0, stream>>>(Wo, wob, 262144);
  k_prep_small<<<1, 64, 0, stream>>>(bl, pb, gm, bwss, gpos);
  k_prep<<<256, 256, 0, stream>>>(cosp, sinp, mag, gpos, bwss, scaleB, feat);
  k_gemm<0><<<32 * 24, 256, 0, stream>>>(hsb, wcat, 24, 1024, bq, bk, bv, scaleB,
                                         qbuf, kbuf, vT, nullptr, nullptr, nullptr);
  k_attn<<<1024, 256, 0, stream>>>(qbuf, kbuf, vT, feat, mask, ctx);
  k_gemm<1><<<32 * 8, 256, 0, stream>>>(ctx, wob, 8, 1024, nullptr, nullptr, nullptr,
                                        nullptr, nullptr, nullptr, nullptr, bo, hs, xbuf);
  k_ln<<<4096, 256, 0, stream>>>(xbuf, lw, lbv, outp);
}